// Round 1
// baseline (616.962 us; speedup 1.0000x reference)
//
#include <hip/hip_runtime.h>
#include <hip/hip_bf16.h>
#include <math.h>

// Problem constants
#define B_   2
#define T_   2048
#define D_   1024
#define H_   16
#define DH_  64
#define DFF_ 4096
#define NTOK (B_*T_)

typedef __attribute__((ext_vector_type(8))) short short8;  // 8 x bf16 bits
typedef __attribute__((ext_vector_type(4))) float f32x4;

__device__ __forceinline__ short f2bf(float f) {
    __hip_bfloat16 h = __float2bfloat16(f);
    union { __hip_bfloat16 h; short s; } u;
    u.h = h;
    return u.s;
}

__device__ __forceinline__ f32x4 mfma16(short8 a, short8 b, f32x4 c) {
    return __builtin_amdgcn_mfma_f32_16x16x32_bf16(a, b, c, 0, 0, 0);
}

// ---------------------------------------------------------------------------
// Weight transpose + cast: src [K][N] f32 row-major -> dst [N][K] bf16
// ---------------------------------------------------------------------------
__global__ __launch_bounds__(256) void transpose_cast(
    const float* __restrict__ src, short* __restrict__ dst, int K, int N)
{
    __shared__ short tile[32][33];
    const int k0 = blockIdx.y * 32, n0 = blockIdx.x * 32;
    const int tx = threadIdx.x, ty = threadIdx.y;  // (32, 8)
    #pragma unroll
    for (int j = 0; j < 4; ++j) {
        int k = ty + j * 8;
        tile[k][tx] = f2bf(src[(size_t)(k0 + k) * N + n0 + tx]);
    }
    __syncthreads();
    #pragma unroll
    for (int j = 0; j < 4; ++j) {
        int n = ty + j * 8;
        dst[(size_t)(n0 + n) * K + k0 + tx] = tile[tx][n];
    }
}

// ---------------------------------------------------------------------------
// LayerNorm over D=1024, f32 in -> bf16 out. One block (256 thr) per row.
// ---------------------------------------------------------------------------
__global__ __launch_bounds__(256) void ln_kernel(
    const float* __restrict__ in, const float* __restrict__ gamma,
    const float* __restrict__ beta, short* __restrict__ out)
{
    const int row = blockIdx.x;
    const int t = threadIdx.x;
    const float4 v = *reinterpret_cast<const float4*>(in + (size_t)row * D_ + t * 4);
    float s  = v.x + v.y + v.z + v.w;
    float sq = v.x*v.x + v.y*v.y + v.z*v.z + v.w*v.w;
    #pragma unroll
    for (int off = 32; off >= 1; off >>= 1) {
        s  += __shfl_xor(s, off);
        sq += __shfl_xor(sq, off);
    }
    __shared__ float ps[4], pq[4];
    if ((t & 63) == 0) { ps[t >> 6] = s; pq[t >> 6] = sq; }
    __syncthreads();
    s  = ps[0] + ps[1] + ps[2] + ps[3];
    sq = pq[0] + pq[1] + pq[2] + pq[3];
    const float mean = s * (1.0f / D_);
    float var = sq * (1.0f / D_) - mean * mean;
    var = fmaxf(var, 0.0f);
    const float rstd = rsqrtf(var + 1e-5f);
    const float4 g = *reinterpret_cast<const float4*>(gamma + t * 4);
    const float4 b = *reinterpret_cast<const float4*>(beta  + t * 4);
    short4 o;
    o.x = f2bf(g.x * ((v.x - mean) * rstd) + b.x);
    o.y = f2bf(g.y * ((v.y - mean) * rstd) + b.y);
    o.z = f2bf(g.z * ((v.z - mean) * rstd) + b.z);
    o.w = f2bf(g.w * ((v.w - mean) * rstd) + b.w);
    *reinterpret_cast<short4*>(out + (size_t)row * D_ + t * 4) = o;
}

// ---------------------------------------------------------------------------
// GEMM: C[M,N] = A[M,K] * B[K,N], A bf16 [M][K], Bt bf16 [N][K] (pre-transposed)
// EPI 0: out bf16 = acc
// EPI 1: out f32  = resid + acc
// EPI 2: out bf16 = gelu(acc + bias)
// EPI 3: out f32  = resid + acc + bias
// Block = 256 threads (4 waves), wave grid WR x WC, tile BM x BN, BK = 64.
// ---------------------------------------------------------------------------
template<int BM, int BN, int WR, int WC, int EPI>
__global__ __launch_bounds__(256) void gemm_kernel(
    const short* __restrict__ A, const short* __restrict__ Bt,
    void* __restrict__ Cout, const float* __restrict__ resid,
    const float* __restrict__ bias, int M, int N, int K)
{
    constexpr int MB = BM / WR / 16;
    constexpr int NB = BN / WC / 16;
    __shared__ short As[BM][72];   // 144 B row stride: 16B-aligned, low bank conflict
    __shared__ short Bs[BN][72];
    const int t = threadIdx.x;
    const int wid = t >> 6, lane = t & 63;
    const int lr = lane & 15, lk = lane >> 4;
    const int m0 = blockIdx.y * BM, n0 = blockIdx.x * BN;
    const int wrow = (wid / WC) * (BM / WR);
    const int wcol = (wid % WC) * (BN / WC);

    const f32x4 fz = {0.f, 0.f, 0.f, 0.f};
    f32x4 acc[MB][NB];
    #pragma unroll
    for (int m = 0; m < MB; ++m)
        #pragma unroll
        for (int n = 0; n < NB; ++n) acc[m][n] = fz;

    for (int k0 = 0; k0 < K; k0 += 64) {
        #pragma unroll
        for (int i = t; i < BM * 8; i += 256) {
            int r = i >> 3, c = i & 7;
            *reinterpret_cast<short8*>(&As[r][c * 8]) =
                *reinterpret_cast<const short8*>(A + (size_t)(m0 + r) * K + k0 + c * 8);
        }
        #pragma unroll
        for (int i = t; i < BN * 8; i += 256) {
            int r = i >> 3, c = i & 7;
            *reinterpret_cast<short8*>(&Bs[r][c * 8]) =
                *reinterpret_cast<const short8*>(Bt + (size_t)(n0 + r) * K + k0 + c * 8);
        }
        __syncthreads();
        #pragma unroll
        for (int kk = 0; kk < 64; kk += 32) {
            short8 af[MB], bf[NB];
            #pragma unroll
            for (int m = 0; m < MB; ++m)
                af[m] = *reinterpret_cast<const short8*>(&As[wrow + m * 16 + lr][kk + lk * 8]);
            #pragma unroll
            for (int n = 0; n < NB; ++n)
                bf[n] = *reinterpret_cast<const short8*>(&Bs[wcol + n * 16 + lr][kk + lk * 8]);
            #pragma unroll
            for (int m = 0; m < MB; ++m)
                #pragma unroll
                for (int n = 0; n < NB; ++n)
                    acc[m][n] = mfma16(af[m], bf[n], acc[m][n]);
        }
        __syncthreads();
    }

    #pragma unroll
    for (int m = 0; m < MB; ++m) {
        #pragma unroll
        for (int n = 0; n < NB; ++n) {
            #pragma unroll
            for (int r = 0; r < 4; ++r) {
                const int gr = m0 + wrow + m * 16 + lk * 4 + r;
                const int gc = n0 + wcol + n * 16 + lr;
                const size_t idx = (size_t)gr * N + gc;
                const float v = acc[m][n][r];
                if constexpr (EPI == 0) {
                    ((short*)Cout)[idx] = f2bf(v);
                } else if constexpr (EPI == 1) {
                    ((float*)Cout)[idx] = resid[idx] + v;
                } else if constexpr (EPI == 2) {
                    const float tt = v + bias[gc];
                    const float ge = 0.5f * tt * (1.0f + erff(tt * 0.70710678118654752f));
                    ((short*)Cout)[idx] = f2bf(ge);
                } else {
                    ((float*)Cout)[idx] = resid[idx] + v + bias[gc];
                }
            }
        }
    }
}

// ---------------------------------------------------------------------------
// V transpose: qkv v-part (b,t,h,dh) -> vT [b][h][dh][T]
// ---------------------------------------------------------------------------
__global__ __launch_bounds__(512) void vtrans(
    const short* __restrict__ qkv, short* __restrict__ vT)
{
    __shared__ short tile[64][65];
    const int qt = blockIdx.x;           // t tile
    const int bh = blockIdx.y;
    const int b = bh >> 4, h = bh & 15;
    const int tx = threadIdx.x, ty = threadIdx.y;  // (64, 8)
    const short* src = qkv + ((size_t)(b * T_ + qt * 64)) * 3072 + 2048 + h * 64;
    #pragma unroll
    for (int j = 0; j < 8; ++j) {
        int tl = ty + j * 8;
        tile[tl][tx] = src[(size_t)tl * 3072 + tx];
    }
    __syncthreads();
    short* dst = vT + ((size_t)bh * 64) * T_ + qt * 64;
    #pragma unroll
    for (int j = 0; j < 8; ++j) {
        int dh = ty + j * 8;
        dst[(size_t)dh * T_ + tx] = tile[tx][dh];
    }
}

// ---------------------------------------------------------------------------
// Causal flash attention. Grid (T/64, B*H), 256 threads = 4 independent waves.
// Wave w handles q rows [qt*64 + w*16, +16). K read from qkv, V from vT.
// ---------------------------------------------------------------------------
__global__ __launch_bounds__(256) void attn_kernel(
    const short* __restrict__ qkv, const short* __restrict__ vT,
    short* __restrict__ attn)
{
    __shared__ short Pl[4][16][40];  // per-wave P tile [16 q][32 kv], 80 B stride
    const int qt = (int)gridDim.x - 1 - (int)blockIdx.x;  // big tiles first
    const int bh = blockIdx.y;
    const int b = bh >> 4, h = bh & 15;
    const int w = threadIdx.x >> 6, lane = threadIdx.x & 63;
    const int lr = lane & 15, lk = lane >> 4;
    const int q0 = qt * 64 + w * 16;

    const short* qrow = qkv + ((size_t)(b * T_ + q0 + lr)) * 3072 + h * 64;
    const short8 qf0 = *reinterpret_cast<const short8*>(qrow + lk * 8);
    const short8 qf1 = *reinterpret_cast<const short8*>(qrow + 32 + lk * 8);
    const short* kbase = qkv + (size_t)b * T_ * 3072 + 1024 + h * 64;
    const short* vbase = vT + (size_t)bh * 64 * T_;

    const f32x4 fz = {0.f, 0.f, 0.f, 0.f};
    f32x4 o0 = fz, o1 = fz, o2 = fz, o3 = fz;
    float mr[4] = {-INFINITY, -INFINITY, -INFINITY, -INFINITY};
    float ls[4] = {0.f, 0.f, 0.f, 0.f};

    const int ktmax = (q0 + 15) >> 5;
    for (int kt = 0; kt <= ktmax; ++kt) {
        const int kvb = kt * 32;
        f32x4 s0 = fz, s1 = fz;
        const short* kp0 = kbase + (size_t)(kvb + lr) * 3072;
        const short* kp1 = kbase + (size_t)(kvb + 16 + lr) * 3072;
        s0 = mfma16(qf0, *reinterpret_cast<const short8*>(kp0 + lk * 8), s0);
        s0 = mfma16(qf1, *reinterpret_cast<const short8*>(kp0 + 32 + lk * 8), s0);
        s1 = mfma16(qf0, *reinterpret_cast<const short8*>(kp1 + lk * 8), s1);
        s1 = mfma16(qf1, *reinterpret_cast<const short8*>(kp1 + 32 + lk * 8), s1);

        const int c0 = kvb + lr, c1 = kvb + 16 + lr;
        #pragma unroll
        for (int r = 0; r < 4; ++r) {
            const int qg = q0 + lk * 4 + r;
            float a  = (c0 <= qg) ? s0[r] * 0.125f : -INFINITY;
            float bb = (c1 <= qg) ? s1[r] * 0.125f : -INFINITY;
            float mx = fmaxf(a, bb);
            mx = fmaxf(mx, __shfl_xor(mx, 1));
            mx = fmaxf(mx, __shfl_xor(mx, 2));
            mx = fmaxf(mx, __shfl_xor(mx, 4));
            mx = fmaxf(mx, __shfl_xor(mx, 8));
            const float mn = fmaxf(mr[r], mx);
            const float alpha = __expf(mr[r] - mn);
            const float pa = __expf(a - mn);
            const float pb = __expf(bb - mn);
            float ts = pa + pb;
            ts += __shfl_xor(ts, 1);
            ts += __shfl_xor(ts, 2);
            ts += __shfl_xor(ts, 4);
            ts += __shfl_xor(ts, 8);
            ls[r] = ls[r] * alpha + ts;
            mr[r] = mn;
            o0[r] *= alpha; o1[r] *= alpha; o2[r] *= alpha; o3[r] *= alpha;
            Pl[w][lk * 4 + r][lr]      = f2bf(pa);
            Pl[w][lk * 4 + r][16 + lr] = f2bf(pb);
        }
        // all 64 lanes' Pl writes must land before cross-lane read-back
        asm volatile("s_waitcnt lgkmcnt(0)" ::: "memory");
        const short8 pf = *reinterpret_cast<const short8*>(&Pl[w][lr][lk * 8]);
        const short* vp = vbase + kvb + lk * 8;
        o0 = mfma16(pf, *reinterpret_cast<const short8*>(vp + (size_t)(lr)      * T_), o0);
        o1 = mfma16(pf, *reinterpret_cast<const short8*>(vp + (size_t)(16 + lr) * T_), o1);
        o2 = mfma16(pf, *reinterpret_cast<const short8*>(vp + (size_t)(32 + lr) * T_), o2);
        o3 = mfma16(pf, *reinterpret_cast<const short8*>(vp + (size_t)(48 + lr) * T_), o3);
    }

    #pragma unroll
    for (int r = 0; r < 4; ++r) {
        const float inv = 1.0f / ls[r];
        short* op = attn + ((size_t)(b * T_ + q0 + lk * 4 + r)) * D_ + h * 64;
        op[lr]      = f2bf(o0[r] * inv);
        op[16 + lr] = f2bf(o1[r] * inv);
        op[32 + lr] = f2bf(o2[r] * inv);
        op[48 + lr] = f2bf(o3[r] * inv);
    }
}

// ---------------------------------------------------------------------------
extern "C" void kernel_launch(void* const* d_in, const int* in_sizes, int n_in,
                              void* d_out, int out_size, void* d_ws, size_t ws_size,
                              hipStream_t stream)
{
    (void)in_sizes; (void)n_in; (void)out_size; (void)ws_size;
    const float* x      = (const float*)d_in[0];
    // d_in[1] = causal_mask (bool) — causality handled analytically
    const float* gamma1 = (const float*)d_in[2];
    const float* beta1  = (const float*)d_in[3];
    const float* wq     = (const float*)d_in[4];
    const float* wk     = (const float*)d_in[5];
    const float* wv     = (const float*)d_in[6];
    const float* wo     = (const float*)d_in[7];
    const float* gamma2 = (const float*)d_in[8];
    const float* beta2  = (const float*)d_in[9];
    const float* w1     = (const float*)d_in[10];
    const float* b1     = (const float*)d_in[11];
    const float* w2     = (const float*)d_in[12];
    const float* b2     = (const float*)d_in[13];
    float* out = (float*)d_out;

    char* ws = (char*)d_ws;
    size_t off = 0;
    short* wqkvT = (short*)(ws + off); off += (size_t)3072 * 1024 * 2;   // [3072][1024]
    short* woT   = (short*)(ws + off); off += (size_t)1024 * 1024 * 2;   // [1024][1024]
    short* w1T   = (short*)(ws + off); off += (size_t)4096 * 1024 * 2;   // [4096][1024]
    short* w2T   = (short*)(ws + off); off += (size_t)1024 * 4096 * 2;   // [1024][4096]
    short* h1    = (short*)(ws + off); off += (size_t)NTOK * 1024 * 2;
    short* h2    = (short*)(ws + off); off += (size_t)NTOK * 1024 * 2;
    float* y     = (float*)(ws + off); off += (size_t)NTOK * 1024 * 4;
    short* attn  = (short*)(ws + off); off += (size_t)NTOK * 1024 * 2;
    short* qkv   = (short*)(ws + off); off += (size_t)NTOK * 3072 * 2;   // [4096][3072]
    short* vT    = (short*)(ws + off); off += (size_t)B_ * H_ * DH_ * T_ * 2;
    short* g     = qkv;  // FFN intermediate [4096][4096] aliases qkv+vT (dead by then)

    const dim3 tb(32, 8);
    transpose_cast<<<dim3(32, 32),  tb, 0, stream>>>(wq, wqkvT,               1024, 1024);
    transpose_cast<<<dim3(32, 32),  tb, 0, stream>>>(wk, wqkvT + 1024 * 1024, 1024, 1024);
    transpose_cast<<<dim3(32, 32),  tb, 0, stream>>>(wv, wqkvT + 2048 * 1024, 1024, 1024);
    transpose_cast<<<dim3(32, 32),  tb, 0, stream>>>(wo, woT,                 1024, 1024);
    transpose_cast<<<dim3(128, 32), tb, 0, stream>>>(w1, w1T, 1024, 4096);
    transpose_cast<<<dim3(32, 128), tb, 0, stream>>>(w2, w2T, 4096, 1024);

    ln_kernel<<<NTOK, 256, 0, stream>>>(x, gamma1, beta1, h1);

    gemm_kernel<128, 128, 2, 2, 0><<<dim3(3072 / 128, NTOK / 128), 256, 0, stream>>>(
        h1, wqkvT, qkv, nullptr, nullptr, NTOK, 3072, 1024);

    vtrans<<<dim3(T_ / 64, B_ * H_), dim3(64, 8), 0, stream>>>(qkv, vT);

    attn_kernel<<<dim3(T_ / 64, B_ * H_), 256, 0, stream>>>(qkv, vT, attn);

    gemm_kernel<128, 64, 4, 1, 1><<<dim3(1024 / 64, NTOK / 128), 256, 0, stream>>>(
        attn, woT, y, x, nullptr, NTOK, 1024, 1024);

    ln_kernel<<<NTOK, 256, 0, stream>>>(y, gamma2, beta2, h2);

    gemm_kernel<128, 128, 2, 2, 2><<<dim3(4096 / 128, NTOK / 128), 256, 0, stream>>>(
        h2, w1T, g, nullptr, b1, NTOK, 4096, 1024);

    gemm_kernel<128, 64, 4, 1, 3><<<dim3(1024 / 64, NTOK / 128), 256, 0, stream>>>(
        g, w2T, out, y, b2, NTOK, 1024, 4096);
}

// Round 2
// 320.199 us; speedup vs baseline: 1.9268x; 1.9268x over previous
//
#include <hip/hip_runtime.h>
#include <hip/hip_bf16.h>
#include <math.h>

// Problem constants
#define B_   2
#define T_   2048
#define D_   1024
#define H_   16
#define DH_  64
#define DFF_ 4096
#define NTOK (B_*T_)

typedef __attribute__((ext_vector_type(8))) short short8;  // 8 x bf16 bits
typedef __attribute__((ext_vector_type(4))) float f32x4;

static __device__ __forceinline__ short f2bf(float f) {
    union { __hip_bfloat16 h; short s; } u;
    u.h = __float2bfloat16(f);
    return u.s;
}

static __device__ __forceinline__ f32x4 mfma16(short8 a, short8 b, f32x4 c) {
    return __builtin_amdgcn_mfma_f32_16x16x32_bf16(a, b, c, 0, 0, 0);
}

// async global->LDS, 16 B per lane; lds dst must be wave-uniform base
static __device__ __forceinline__ void gload16(const void* g, void* l) {
    __builtin_amdgcn_global_load_lds(
        (__attribute__((address_space(1))) void*)g,
        (__attribute__((address_space(3))) void*)l, 16, 0, 0);
}

// Swizzled b128 read from a [rows][64] bf16 tile (128 B row stride).
// Pairs with staging that XORs the in-row byte offset with ((row&7)<<4):
// 16-way bank conflict -> 2-way (free).
static __device__ __forceinline__ short8 lds_read_sw(const short* base, int row, int kbyte) {
    const int off = (row << 7) + (kbyte ^ ((row & 7) << 4));
    return *reinterpret_cast<const short8*>(reinterpret_cast<const char*>(base) + off);
}

// ---------------------------------------------------------------------------
// Weight transpose + cast (+scale): src [K][N] f32 -> dst [N][K] bf16
// ---------------------------------------------------------------------------
__global__ __launch_bounds__(256) void transpose_cast(
    const float* __restrict__ src, short* __restrict__ dst, int K, int N, float scale)
{
    __shared__ short tile[32][33];
    const int k0 = blockIdx.y * 32, n0 = blockIdx.x * 32;
    const int tx = threadIdx.x, ty = threadIdx.y;  // (32, 8)
    #pragma unroll
    for (int j = 0; j < 4; ++j) {
        int k = ty + j * 8;
        tile[k][tx] = f2bf(src[(size_t)(k0 + k) * N + n0 + tx] * scale);
    }
    __syncthreads();
    #pragma unroll
    for (int j = 0; j < 4; ++j) {
        int n = ty + j * 8;
        dst[(size_t)(n0 + n) * K + k0 + tx] = tile[tx][n];
    }
}

// ---------------------------------------------------------------------------
// LayerNorm over D=1024, f32 in -> bf16 out. One block (256 thr) per row.
// ---------------------------------------------------------------------------
__global__ __launch_bounds__(256) void ln_kernel(
    const float* __restrict__ in, const float* __restrict__ gamma,
    const float* __restrict__ beta, short* __restrict__ out)
{
    const int row = blockIdx.x;
    const int t = threadIdx.x;
    const float4 v = *reinterpret_cast<const float4*>(in + (size_t)row * D_ + t * 4);
    float s  = v.x + v.y + v.z + v.w;
    float sq = v.x*v.x + v.y*v.y + v.z*v.z + v.w*v.w;
    #pragma unroll
    for (int off = 32; off >= 1; off >>= 1) {
        s  += __shfl_xor(s, off);
        sq += __shfl_xor(sq, off);
    }
    __shared__ float ps[4], pq[4];
    if ((t & 63) == 0) { ps[t >> 6] = s; pq[t >> 6] = sq; }
    __syncthreads();
    s  = ps[0] + ps[1] + ps[2] + ps[3];
    sq = pq[0] + pq[1] + pq[2] + pq[3];
    const float mean = s * (1.0f / D_);
    float var = sq * (1.0f / D_) - mean * mean;
    var = fmaxf(var, 0.0f);
    const float rstd = rsqrtf(var + 1e-5f);
    const float4 g = *reinterpret_cast<const float4*>(gamma + t * 4);
    const float4 b = *reinterpret_cast<const float4*>(beta  + t * 4);
    short4 o;
    o.x = f2bf(g.x * ((v.x - mean) * rstd) + b.x);
    o.y = f2bf(g.y * ((v.y - mean) * rstd) + b.y);
    o.z = f2bf(g.z * ((v.z - mean) * rstd) + b.z);
    o.w = f2bf(g.w * ((v.w - mean) * rstd) + b.w);
    *reinterpret_cast<short4*>(out + (size_t)row * D_ + t * 4) = o;
}

// ---------------------------------------------------------------------------
// GEMM (m97 structure): C[M,N] = A[M,K] * Bt[N,K]^T, 128x128 tile, BK=64,
// 4 waves, global_load_lds width-16 staging, swizzled linear LDS,
// bijective XCD-chunked block swizzle (requires gridDim.x % 8 == 0).
// EPI 0: out bf16 = acc
// EPI 1: out f32  = resid + acc
// EPI 2: out bf16 = gelu(acc + bias)
// EPI 3: out f32  = resid + acc + bias
// ---------------------------------------------------------------------------
template<int EPI>
__global__ __launch_bounds__(256) void gemm_kernel(
    const short* __restrict__ A, const short* __restrict__ Bt,
    void* __restrict__ Cout, const float* __restrict__ resid,
    const float* __restrict__ bias, int M, int N, int K, int nbx)
{
    __shared__ short As[8192];   // [128][64] linear, source-swizzled
    __shared__ short Bs[8192];
    const int t = threadIdx.x;
    const int wid = t >> 6, lane = t & 63;
    const int lr = lane & 15, lk = lane >> 4;
    const int cpx = (int)gridDim.x >> 3;
    const int bid = (int)blockIdx.x;
    const int swz = (bid & 7) * cpx + (bid >> 3);   // XCD gets contiguous chunk
    const int m0 = (swz / nbx) * 128, n0 = (swz % nbx) * 128;
    const int wrow = (wid >> 1) * 64, wcol = (wid & 1) * 64;

    f32x4 acc[4][4];
    #pragma unroll
    for (int m = 0; m < 4; ++m)
        #pragma unroll
        for (int n = 0; n < 4; ++n) acc[m][n] = (f32x4){0.f, 0.f, 0.f, 0.f};

    for (int k0 = 0; k0 < K; k0 += 64) {
        #pragma unroll
        for (int j = 0; j < 4; ++j) {
            const int off = j * 4096 + t * 16;           // byte offset in tile
            const int r   = off >> 7;                    // tile row
            const int cb  = (off & 127) ^ ((r & 7) << 4);// swizzled in-row byte
            gload16(A  + (size_t)(m0 + r) * K + k0 + (cb >> 1),
                    (char*)As + j * 4096 + wid * 1024);
            gload16(Bt + (size_t)(n0 + r) * K + k0 + (cb >> 1),
                    (char*)Bs + j * 4096 + wid * 1024);
        }
        __syncthreads();   // compiler drains vmcnt(0) before barrier
        #pragma unroll
        for (int kk = 0; kk < 64; kk += 32) {
            short8 af[4], bf[4];
            #pragma unroll
            for (int m = 0; m < 4; ++m)
                af[m] = lds_read_sw(As, wrow + m * 16 + lr, (kk + lk * 8) * 2);
            #pragma unroll
            for (int n = 0; n < 4; ++n)
                bf[n] = lds_read_sw(Bs, wcol + n * 16 + lr, (kk + lk * 8) * 2);
            #pragma unroll
            for (int m = 0; m < 4; ++m)
                #pragma unroll
                for (int n = 0; n < 4; ++n)
                    acc[m][n] = mfma16(af[m], bf[n], acc[m][n]);
        }
        __syncthreads();
    }

    #pragma unroll
    for (int m = 0; m < 4; ++m) {
        #pragma unroll
        for (int n = 0; n < 4; ++n) {
            #pragma unroll
            for (int r = 0; r < 4; ++r) {
                const int gr = m0 + wrow + m * 16 + lk * 4 + r;
                const int gc = n0 + wcol + n * 16 + lr;
                const size_t idx = (size_t)gr * N + gc;
                const float v = acc[m][n][r];
                if constexpr (EPI == 0) {
                    ((short*)Cout)[idx] = f2bf(v);
                } else if constexpr (EPI == 1) {
                    ((float*)Cout)[idx] = resid[idx] + v;
                } else if constexpr (EPI == 2) {
                    const float tt = v + bias[gc];
                    const float ge = 0.5f * tt * (1.0f + erff(tt * 0.70710678118654752f));
                    ((short*)Cout)[idx] = f2bf(ge);
                } else {
                    ((float*)Cout)[idx] = resid[idx] + v + bias[gc];
                }
            }
        }
    }
}

// ---------------------------------------------------------------------------
// V transpose: qkv v-part (b,t,h,dh) -> vT [b][h][dh][T]
// ---------------------------------------------------------------------------
__global__ __launch_bounds__(512) void vtrans(
    const short* __restrict__ qkv, short* __restrict__ vT)
{
    __shared__ short tile[64][65];
    const int qt = blockIdx.x;
    const int bh = blockIdx.y;
    const int b = bh >> 4, h = bh & 15;
    const int tx = threadIdx.x, ty = threadIdx.y;  // (64, 8)
    const short* src = qkv + ((size_t)(b * T_ + qt * 64)) * 3072 + 2048 + h * 64;
    #pragma unroll
    for (int j = 0; j < 8; ++j) {
        int tl = ty + j * 8;
        tile[tl][tx] = src[(size_t)tl * 3072 + tx];
    }
    __syncthreads();
    short* dst = vT + ((size_t)bh * 64) * T_ + qt * 64;
    #pragma unroll
    for (int j = 0; j < 8; ++j) {
        int dh = ty + j * 8;
        dst[(size_t)dh * T_ + tx] = tile[tx][dh];
    }
}

// ---------------------------------------------------------------------------
// Causal flash attention, block-cooperative.
// Grid (T/64, B*H), 256 threads = 4 waves; wave w owns q rows [qt*64+w*16,+16).
// K tile [64][64] and V^T tile [64 dh][64 kv] staged to LDS via global_load_lds
// (source-swizzled), double-buffered 2-phase. Q pre-scaled (0.125 folded into
// wq). Softmax: defer-max (THR=8) -> shfl-free steady state; per-lane partial
// row-sums reduced once at the end.
// ---------------------------------------------------------------------------
__global__ __launch_bounds__(256) void attn_kernel(
    const short* __restrict__ qkv, const short* __restrict__ vT,
    short* __restrict__ attn)
{
    __shared__ short Ks[2][4096];
    __shared__ short Vs[2][4096];
    __shared__ short Ps[4][16 * 72];   // per-wave P tile, 144 B row stride
    const int qt = (int)gridDim.x - 1 - (int)blockIdx.x;  // heavy blocks first
    const int bh = blockIdx.y;
    const int b = bh >> 4, h = bh & 15;
    const int t = threadIdx.x;
    const int wid = t >> 6, lane = t & 63;
    const int lr = lane & 15, lk = lane >> 4;
    const int q0 = qt * 64 + wid * 16;

    const short* qrow = qkv + (size_t)(b * T_ + q0 + lr) * 3072 + h * 64;
    const short8 qf0 = *reinterpret_cast<const short8*>(qrow + lk * 8);
    const short8 qf1 = *reinterpret_cast<const short8*>(qrow + 32 + lk * 8);
    const short* kbase = qkv + (size_t)b * T_ * 3072 + 1024 + h * 64;
    const short* vbase = vT + (size_t)bh * 64 * T_;

    f32x4 o[4];
    float mr[4], lsp[4];
    #pragma unroll
    for (int n = 0; n < 4; ++n) o[n] = (f32x4){0.f, 0.f, 0.f, 0.f};
    #pragma unroll
    for (int r = 0; r < 4; ++r) { mr[r] = -INFINITY; lsp[r] = 0.f; }

    const int nkt = qt + 1;

    #pragma unroll
    for (int j = 0; j < 2; ++j) {   // stage tile 0
        const int off = j * 4096 + t * 16;
        const int r   = off >> 7;
        const int cb  = (off & 127) ^ ((r & 7) << 4);
        gload16(kbase + (size_t)r * 3072 + (cb >> 1), (char*)Ks[0] + j * 4096 + wid * 1024);
        gload16(vbase + (size_t)r * T_   + (cb >> 1), (char*)Vs[0] + j * 4096 + wid * 1024);
    }
    __syncthreads();

    int cur = 0;
    for (int kt = 0; kt < nkt; ++kt) {
        const int kvb = kt * 64;
        if (kt + 1 < nkt) {   // prefetch next tile into other buffer
            const int nb = kvb + 64;
            #pragma unroll
            for (int j = 0; j < 2; ++j) {
                const int off = j * 4096 + t * 16;
                const int r   = off >> 7;
                const int cb  = (off & 127) ^ ((r & 7) << 4);
                gload16(kbase + (size_t)(nb + r) * 3072 + (cb >> 1),
                        (char*)Ks[cur ^ 1] + j * 4096 + wid * 1024);
                gload16(vbase + (size_t)r * T_ + nb + (cb >> 1),
                        (char*)Vs[cur ^ 1] + j * 4096 + wid * 1024);
            }
        }

        // QK^T: S[16 q][64 kv]
        f32x4 s[4];
        #pragma unroll
        for (int n = 0; n < 4; ++n) s[n] = (f32x4){0.f, 0.f, 0.f, 0.f};
        #pragma unroll
        for (int n = 0; n < 4; ++n) {
            s[n] = mfma16(qf0, lds_read_sw(Ks[cur], n * 16 + lr, (lk * 8) * 2), s[n]);
            s[n] = mfma16(qf1, lds_read_sw(Ks[cur], n * 16 + lr, (32 + lk * 8) * 2), s[n]);
        }

        const bool diag = (kt == qt);
        #pragma unroll
        for (int r = 0; r < 4; ++r) {
            const int qg = q0 + lk * 4 + r;
            float v0 = s[0][r], v1 = s[1][r], v2 = s[2][r], v3 = s[3][r];
            if (diag) {
                if (kvb +      lr > qg) v0 = -INFINITY;
                if (kvb + 16 + lr > qg) v1 = -INFINITY;
                if (kvb + 32 + lr > qg) v2 = -INFINITY;
                if (kvb + 48 + lr > qg) v3 = -INFINITY;
            }
            const float mxl = fmaxf(fmaxf(v0, v1), fmaxf(v2, v3));
            if (!__all(mxl <= mr[r] + 8.0f)) {     // wave-uniform, rare
                float mx = mxl;
                mx = fmaxf(mx, __shfl_xor(mx, 1));
                mx = fmaxf(mx, __shfl_xor(mx, 2));
                mx = fmaxf(mx, __shfl_xor(mx, 4));
                mx = fmaxf(mx, __shfl_xor(mx, 8));
                const float mnew = fmaxf(mr[r], mx);
                const float alpha = __expf(mr[r] - mnew);
                o[0][r] *= alpha; o[1][r] *= alpha; o[2][r] *= alpha; o[3][r] *= alpha;
                lsp[r] *= alpha;
                mr[r] = mnew;
            }
            const float p0 = __expf(v0 - mr[r]);
            const float p1 = __expf(v1 - mr[r]);
            const float p2 = __expf(v2 - mr[r]);
            const float p3 = __expf(v3 - mr[r]);
            lsp[r] += p0 + p1 + p2 + p3;
            short* pr = &Ps[wid][(lk * 4 + r) * 72];
            pr[lr]      = f2bf(p0);
            pr[16 + lr] = f2bf(p1);
            pr[32 + lr] = f2bf(p2);
            pr[48 + lr] = f2bf(p3);
        }
        // all lanes' Ps writes must land before cross-lane read-back
        asm volatile("s_waitcnt lgkmcnt(0)" ::: "memory");

        // PV: O += P[16][64] * V[64][64]
        #pragma unroll
        for (int kk = 0; kk < 2; ++kk) {
            const short8 pf = *reinterpret_cast<const short8*>(
                &Ps[wid][lr * 72 + kk * 32 + lk * 8]);
            #pragma unroll
            for (int n = 0; n < 4; ++n)
                o[n] = mfma16(pf, lds_read_sw(Vs[cur], n * 16 + lr, (kk * 32 + lk * 8) * 2), o[n]);
        }
        __syncthreads();   // drains prefetch vmcnt + protects Ks/Vs/Ps reuse
        cur ^= 1;
    }

    #pragma unroll
    for (int r = 0; r < 4; ++r) {
        float l = lsp[r];
        l += __shfl_xor(l, 1);
        l += __shfl_xor(l, 2);
        l += __shfl_xor(l, 4);
        l += __shfl_xor(l, 8);
        const float inv = 1.0f / l;
        short* op = attn + (size_t)(b * T_ + q0 + lk * 4 + r) * D_ + h * 64;
        #pragma unroll
        for (int n = 0; n < 4; ++n)
            op[n * 16 + lr] = f2bf(o[n][r] * inv);
    }
}

// ---------------------------------------------------------------------------
extern "C" void kernel_launch(void* const* d_in, const int* in_sizes, int n_in,
                              void* d_out, int out_size, void* d_ws, size_t ws_size,
                              hipStream_t stream)
{
    (void)in_sizes; (void)n_in; (void)out_size; (void)ws_size;
    const float* x      = (const float*)d_in[0];
    // d_in[1] = causal_mask (bool) — causality handled analytically
    const float* gamma1 = (const float*)d_in[2];
    const float* beta1  = (const float*)d_in[3];
    const float* wq     = (const float*)d_in[4];
    const float* wk     = (const float*)d_in[5];
    const float* wv     = (const float*)d_in[6];
    const float* wo     = (const float*)d_in[7];
    const float* gamma2 = (const float*)d_in[8];
    const float* beta2  = (const float*)d_in[9];
    const float* w1     = (const float*)d_in[10];
    const float* b1     = (const float*)d_in[11];
    const float* w2     = (const float*)d_in[12];
    const float* b2     = (const float*)d_in[13];
    float* out = (float*)d_out;

    char* ws = (char*)d_ws;
    size_t off = 0;
    short* wqkvT = (short*)(ws + off); off += (size_t)3072 * 1024 * 2;
    short* woT   = (short*)(ws + off); off += (size_t)1024 * 1024 * 2;
    short* w1T   = (short*)(ws + off); off += (size_t)4096 * 1024 * 2;
    short* w2T   = (short*)(ws + off); off += (size_t)1024 * 4096 * 2;
    short* h1    = (short*)(ws + off); off += (size_t)NTOK * 1024 * 2;
    short* h2    = (short*)(ws + off); off += (size_t)NTOK * 1024 * 2;
    float* y     = (float*)(ws + off); off += (size_t)NTOK * 1024 * 4;
    short* attnb = (short*)(ws + off); off += (size_t)NTOK * 1024 * 2;
    short* qkv   = (short*)(ws + off); off += (size_t)NTOK * 3072 * 2;
    short* vT    = (short*)(ws + off); off += (size_t)B_ * H_ * DH_ * T_ * 2;
    short* g     = qkv;  // FFN intermediate [4096][4096] aliases qkv+vT (dead by then)

    const dim3 tb(32, 8);
    // 1/sqrt(DH)=0.125 folded into wq so Q comes out of the QKV GEMM pre-scaled
    transpose_cast<<<dim3(32, 32),  tb, 0, stream>>>(wq, wqkvT,               1024, 1024, 0.125f);
    transpose_cast<<<dim3(32, 32),  tb, 0, stream>>>(wk, wqkvT + 1024 * 1024, 1024, 1024, 1.0f);
    transpose_cast<<<dim3(32, 32),  tb, 0, stream>>>(wv, wqkvT + 2048 * 1024, 1024, 1024, 1.0f);
    transpose_cast<<<dim3(32, 32),  tb, 0, stream>>>(wo, woT,                 1024, 1024, 1.0f);
    transpose_cast<<<dim3(128, 32), tb, 0, stream>>>(w1, w1T, 1024, 4096, 1.0f);
    transpose_cast<<<dim3(32, 128), tb, 0, stream>>>(w2, w2T, 4096, 1024, 1.0f);

    ln_kernel<<<NTOK, 256, 0, stream>>>(x, gamma1, beta1, h1);

    gemm_kernel<0><<<768, 256, 0, stream>>>(
        h1, wqkvT, qkv, nullptr, nullptr, NTOK, 3072, 1024, 24);

    vtrans<<<dim3(T_ / 64, B_ * H_), dim3(64, 8), 0, stream>>>(qkv, vT);

    attn_kernel<<<dim3(T_ / 64, B_ * H_), 256, 0, stream>>>(qkv, vT, attnb);

    gemm_kernel<1><<<256, 256, 0, stream>>>(
        attnb, woT, y, x, nullptr, NTOK, 1024, 1024, 8);

    ln_kernel<<<NTOK, 256, 0, stream>>>(y, gamma2, beta2, h2);

    gemm_kernel<2><<<1024, 256, 0, stream>>>(
        h2, w1T, g, nullptr, b1, NTOK, 4096, 1024, 32);

    gemm_kernel<3><<<256, 256, 0, stream>>>(
        g, w2T, out, y, b2, NTOK, 1024, 4096, 8);
}